// Round 1
// 244.022 us; speedup vs baseline: 1.1104x; 1.1104x over previous
//
#include <hip/hip_runtime.h>
#include <cstdint>
#include <math.h>

// GeometricAttention: B=4,H=8,N=2048, D = 8*16 (mv, IPF signs on q) + 16 (s) = 144
// R4: 32x32x16 MFMA restructure. 4 waves x 32 Q-rows/block (BM=128), S^T orientation,
// softmax row fully lane-local (1 shfl_xor), P kept in REGISTERS via
// v_cvt_pk_bf16_f32 + permlane32_swap (T12) -> no sP LDS phase, 2 barriers/iter.
// Deferred O-rescale (T13, THR=8). Fused single pack prepass.
// LDS read traffic per block-iter: 380KB -> 194KB (was the bottleneck).

#define BH    32
#define N_    2048
#define DMV   128
#define DS    16
#define D_    144
#define BM    128          // Q rows per block (4 waves x 32 rows)
#define BN    64           // KV rows per iteration
#define NKIT  (N_ / BN)    // 32
#define KSTR  152          // packed K row stride (bf16): 144 data + 8 pad (D=9*16 exact)
#define VSTR  72           // packed V^T row stride (bf16): 64 data + 8 pad
#define SVROWS 160         // sVT rows: 144 data + 16 zero pad (dt=4 tile)
#define KCHUNKS (BN * KSTR / 8)   // 1216 16B chunks
#define VCHUNKS (D_ * VSTR / 8)   // 1296 16B chunks
#define KP_BYTES ((size_t)BH * N_ * KSTR * 2)   // 19,922,944
#define QSCALE 0.12022458674074693f  // (1/12) * log2(e)
#define KPACK_BLOCKS (BH * N_ * 19 / 256)       // 4864

typedef __bf16 bf16_8 __attribute__((ext_vector_type(8)));
typedef float  f32x4  __attribute__((ext_vector_type(4)));
typedef float  f32x16 __attribute__((ext_vector_type(16)));

#define GLOAD_LDS16(g, l)                                                     \
  __builtin_amdgcn_global_load_lds(                                           \
      (const __attribute__((address_space(1))) void*)(g),                     \
      (__attribute__((address_space(3))) void*)(l), 16, 0, 0)

__device__ __forceinline__ f32x16 mfma32(bf16_8 a, bf16_8 b, f32x16 c) {
  return __builtin_amdgcn_mfma_f32_32x32x16_bf16(a, b, c, 0, 0, 0);
}

// ---------------- fused pre-pass: K pack + V^T pack in one launch -------------------
// blocks [0, KPACK_BLOCKS): K -> bf16 [bh*n][152], one thread = one 16B chunk (19/row)
// blocks [KPACK_BLOCKS, +1024): V^T -> bf16 tile-blocked [bh*32 tiles][144][72]
__global__ __launch_bounds__(256)
void pack_kv(const float* __restrict__ kmv, const float* __restrict__ ks_,
             const float* __restrict__ vmv, const float* __restrict__ vs,
             __bf16* __restrict__ kp, __bf16* __restrict__ vt) {
  __shared__ __align__(16) __bf16 sT[D_ * VSTR];   // [d][n], 20736 B (vt branch only)
  const int t = threadIdx.x;
  const int b = blockIdx.x;
  if (b < KPACK_BLOCKS) {
    const unsigned g = b * 256u + t;               // < 65536*19
    const unsigned row = g / 19u, seg = g - row * 19u;
    bf16_8 o;
    if (seg < 16) {
      const f32x4* p = (const f32x4*)(kmv + (size_t)row * DMV + seg * 8);
      f32x4 a = p[0], bb = p[1];
#pragma unroll
      for (int j = 0; j < 8; ++j) o[j] = (__bf16)((j < 4) ? a[j] : bb[j - 4]);
    } else if (seg < 18) {
      const f32x4* p = (const f32x4*)(ks_ + (size_t)row * DS + (seg - 16) * 8);
      f32x4 a = p[0], bb = p[1];
#pragma unroll
      for (int j = 0; j < 8; ++j) o[j] = (__bf16)((j < 4) ? a[j] : bb[j - 4]);
    } else {
#pragma unroll
      for (int j = 0; j < 8; ++j) o[j] = (__bf16)0.0f;
    }
    *(bf16_8*)(kp + (size_t)row * KSTR + seg * 8) = o;
    return;
  }
  // ---- V^T pack: transpose through LDS laid out [d][VSTR], vector b128 read-side ----
  const int tile = b - KPACK_BLOCKS;               // bh*32 + nb
  const int n = t >> 2, c = t & 3;
  const float* mv = vmv + (size_t)(tile * 64 + n) * DMV;
  const float* sv = vs  + (size_t)(tile * 64 + n) * DS;
  if (c < 3) {
#pragma unroll
    for (int i = 0; i < 9; ++i) {
      f32x4 q = *(const f32x4*)(mv + c * 36 + 4 * i);
#pragma unroll
      for (int j = 0; j < 4; ++j) sT[(c * 36 + 4 * i + j) * VSTR + n] = (__bf16)q[j];
    }
  } else {
#pragma unroll
    for (int i = 0; i < 5; ++i) {
      f32x4 q = *(const f32x4*)(mv + 108 + 4 * i);
#pragma unroll
      for (int j = 0; j < 4; ++j) sT[(108 + 4 * i + j) * VSTR + n] = (__bf16)q[j];
    }
#pragma unroll
    for (int i = 0; i < 4; ++i) {
      f32x4 q = *(const f32x4*)(sv + 4 * i);
#pragma unroll
      for (int j = 0; j < 4; ++j) sT[(DMV + 4 * i + j) * VSTR + n] = (__bf16)q[j];
    }
  }
  __syncthreads();
  __bf16* vtt = vt + (size_t)tile * (D_ * VSTR);
#pragma unroll
  for (int s = 0; s < 5; ++s) {     // 1152 data chunks (8 per 72-wide row)
    int idx = t + 256 * s;
    if (idx < D_ * 8) {
      int d = idx >> 3, jc = idx & 7;
      *(bf16_8*)&vtt[d * VSTR + jc * 8] = *(const bf16_8*)&sT[d * VSTR + jc * 8];
    }
  }
}

// ---------------- Q fragment load: IPF sign + scale, fp32 -> bf16 (k0 multiple of 8) --
__device__ __forceinline__ bf16_8 load_q_frag(const float* qmv_row, const float* qs_row, int k0) {
  bf16_8 f;
  if (k0 < DMV) {
    const f32x4* p = (const f32x4*)(qmv_row + k0);
    f32x4 a = p[0], b = p[1];
    // IPF = [1,1,-1,-1,-1,-1,-1,-1, 1,1,1,1,1,1,-1,-1]; k0&8 selects which half.
    int hi8 = k0 & 8;
#pragma unroll
    for (int j = 0; j < 8; ++j) {
      float v = (j < 4) ? a[j] : b[j - 4];
      bool pos = hi8 ? (j < 6) : (j < 2);
      f[j] = (__bf16)(v * (pos ? QSCALE : -QSCALE));
    }
  } else {
    const f32x4* p = (const f32x4*)(qs_row + (k0 - DMV));
    f32x4 a = p[0], b = p[1];
#pragma unroll
    for (int j = 0; j < 8; ++j) {
      float v = (j < 4) ? a[j] : b[j - 4];
      f[j] = (__bf16)(v * QSCALE);
    }
  }
  return f;
}

// ---------------- main flash kernel (256 threads, 4 waves x 32 Q-rows) ---------------
__global__ __launch_bounds__(256, 2)
void geo_attn_kernel(const float* __restrict__ q_mv, const float* __restrict__ q_s,
                     const __bf16* __restrict__ kp, const __bf16* __restrict__ vt,
                     float* __restrict__ out)
{
  __shared__ __align__(16) __bf16 sK[BN * KSTR];       // 19456 B
  __shared__ __align__(16) __bf16 sVT[SVROWS * VSTR];  // 23040 B  (total 42496 B)

  const int tid  = threadIdx.x;
  const int w    = tid >> 6;        // wave 0..3
  const int lane = tid & 63;
  const int c32  = lane & 31;
  const int hi   = lane >> 5;
  const int bh    = blockIdx.y;
  const int qbase = blockIdx.x * BM;
  const size_t bh_n = (size_t)bh * N_;

  // zero the d-pad rows 144..159 of sVT once (staging never touches them)
  if (tid < 144) {
    f32x4 z = {0.f, 0.f, 0.f, 0.f};
    *(f32x4*)((char*)sVT + D_ * VSTR * 2 + tid * 16) = z;
  }

  // ---- Q fragments in registers: B-operand layout, col m = c32, k = ks*16 + hi*8 + j
  bf16_8 qf[9];
  {
    const int mrow = qbase + w * 32 + c32;
    const float* qmv_row = q_mv + (bh_n + mrow) * DMV;
    const float* qs_row  = q_s  + (bh_n + mrow) * DS;
#pragma unroll
    for (int ks = 0; ks < 9; ++ks)
      qf[ks] = load_q_frag(qmv_row, qs_row, ks * 16 + hi * 8);
  }

  f32x16 of[5];
#pragma unroll
  for (int dt = 0; dt < 5; ++dt)
#pragma unroll
    for (int r = 0; r < 16; ++r) of[dt][r] = 0.0f;
  float m_i = -INFINITY, l_i = 0.0f;    // per Q-row stat, row m = c32 (both hi copies)

  const __bf16* kbase = kp + bh_n * KSTR;

  for (int it = 0; it < NKIT; ++it) {
    // ======== stage K,V tiles via global->LDS DMA ========
    {
      const __bf16* kt  = kbase + (size_t)(it * BN) * KSTR;
      const __bf16* vtt = vt + (size_t)(bh * NKIT + it) * (D_ * VSTR);
#pragma unroll
      for (int s = 0; s < 4; ++s)
        GLOAD_LDS16(kt + (tid + 256 * s) * 8, &sK[(tid + 256 * s) * 8]);
      if (tid < KCHUNKS - 1024)   // 192: waves 0..2
        GLOAD_LDS16(kt + (tid + 1024) * 8, &sK[(tid + 1024) * 8]);
#pragma unroll
      for (int s = 0; s < 5; ++s)
        GLOAD_LDS16(vtt + (tid + 256 * s) * 8, &sVT[(tid + 256 * s) * 8]);
      if (tid < VCHUNKS - 1280)   // 16
        GLOAD_LDS16(vtt + (tid + 1280) * 8, &sVT[(tid + 1280) * 8]);
    }
    __syncthreads();   // vmcnt+lgkmcnt drained -> tiles resident

    // ======== S^T = K Q^T : sf[nt] rows n = nt*32 + (r&3)+8*(r>>2)+4*hi, cols m=c32 ==
    f32x16 sf[2];
#pragma unroll
    for (int nt = 0; nt < 2; ++nt)
#pragma unroll
      for (int r = 0; r < 16; ++r) sf[nt][r] = 0.0f;
    __builtin_amdgcn_s_setprio(1);
#pragma unroll
    for (int ks = 0; ks < 9; ++ks) {
      bf16_8 kb0 = *(const bf16_8*)&sK[(c32)      * KSTR + ks * 16 + hi * 8];
      bf16_8 kb1 = *(const bf16_8*)&sK[(32 + c32) * KSTR + ks * 16 + hi * 8];
      sf[0] = mfma32(kb0, qf[ks], sf[0]);
      sf[1] = mfma32(kb1, qf[ks], sf[1]);
    }
    __builtin_amdgcn_s_setprio(0);

    // ======== online softmax: row m = c32 fully lane-local (32 vals) + 1 shuffle ====
    float al = 1.0f, m_use;
    {
      float mx = sf[0][0];
#pragma unroll
      for (int r = 1; r < 16; ++r) mx = fmaxf(mx, sf[0][r]);
#pragma unroll
      for (int r = 0; r < 16; ++r) mx = fmaxf(mx, sf[1][r]);
      mx = fmaxf(mx, __shfl_xor(mx, 32));

      // T13 deferred rescale: keep old max while growth <= 8 (P bounded by 2^8)
      if (__all(mx <= m_i + 8.0f)) {
        m_use = m_i;
      } else {
        float mnew = fmaxf(m_i, mx);
        al = __builtin_amdgcn_exp2f(m_i - mnew);
        m_i = mnew; m_use = mnew;
        // redistribute al to O-row indexing (row m' = (r&3)+8*(r>>2)+4*hi)
#pragma unroll
        for (int r = 0; r < 16; ++r) {
          float a = __shfl(al, (r & 3) + 8 * (r >> 2) + 4 * hi);
#pragma unroll
          for (int dt = 0; dt < 5; ++dt) of[dt][r] *= a;
        }
      }
      float rs = 0.0f;
#pragma unroll
      for (int nt = 0; nt < 2; ++nt)
#pragma unroll
        for (int r = 0; r < 16; ++r) {
          float p = __builtin_amdgcn_exp2f(sf[nt][r] - m_use);
          sf[nt][r] = p;
          rs += p;
        }
      rs += __shfl_xor(rs, 32);
      l_i = l_i * al + rs;
    }

    // ======== O += P V, P assembled in-register (cvt_pk + permlane32_swap) ==========
#pragma unroll
    for (int ks = 0; ks < 4; ++ks) {
      const int nt = ks >> 1;
      const int Ra = 8 * (ks & 1);
      unsigned x0, x1, y0, y1;
      asm("v_cvt_pk_bf16_f32 %0, %1, %2" : "=v"(x0) : "v"(sf[nt][Ra + 0]), "v"(sf[nt][Ra + 1]));
      asm("v_cvt_pk_bf16_f32 %0, %1, %2" : "=v"(x1) : "v"(sf[nt][Ra + 2]), "v"(sf[nt][Ra + 3]));
      asm("v_cvt_pk_bf16_f32 %0, %1, %2" : "=v"(y0) : "v"(sf[nt][Ra + 4]), "v"(sf[nt][Ra + 5]));
      asm("v_cvt_pk_bf16_f32 %0, %1, %2" : "=v"(y1) : "v"(sf[nt][Ra + 6]), "v"(sf[nt][Ra + 7]));
      auto s0 = __builtin_amdgcn_permlane32_swap(x0, y0, false, false);
      auto s1 = __builtin_amdgcn_permlane32_swap(x1, y1, false, false);
      union { unsigned u[4]; bf16_8 v; } pu;
      pu.u[0] = s0[0]; pu.u[1] = s1[0]; pu.u[2] = s0[1]; pu.u[3] = s1[1];
      __builtin_amdgcn_s_setprio(1);
#pragma unroll
      for (int dt = 0; dt < 5; ++dt) {
        bf16_8 vb = *(const bf16_8*)&sVT[(dt * 32 + c32) * VSTR + ks * 16 + hi * 8];
        of[dt] = mfma32(pu.v, vb, of[dt]);
      }
      __builtin_amdgcn_s_setprio(0);
    }
    __syncthreads();  // sK/sVT reads done before next iteration's staging
  }

  // ======== epilogue: O /= l (redistributed to O-rows), write fp32 ========
  float* out_mv = out;
  float* out_s  = out + (size_t)BH * N_ * DMV;
#pragma unroll
  for (int r = 0; r < 16; ++r) {
    const int ml  = (r & 3) + 8 * (r >> 2) + 4 * hi;
    const float linv = __builtin_amdgcn_rcpf(__shfl(l_i, ml));
    const int row = qbase + w * 32 + ml;
#pragma unroll
    for (int dt = 0; dt < 4; ++dt)
      out_mv[(bh_n + row) * DMV + dt * 32 + c32] = of[dt][r] * linv;
    if (c32 < DS)
      out_s[(bh_n + row) * DS + c32] = of[4][r] * linv;
  }
}

extern "C" void kernel_launch(void* const* d_in, const int* in_sizes, int n_in,
                              void* d_out, int out_size, void* d_ws, size_t ws_size,
                              hipStream_t stream) {
  (void)in_sizes; (void)n_in; (void)out_size; (void)ws_size;
  const float* q_mv = (const float*)d_in[0];
  const float* k_mv = (const float*)d_in[1];
  const float* v_mv = (const float*)d_in[2];
  const float* q_s  = (const float*)d_in[3];
  const float* k_s  = (const float*)d_in[4];
  const float* v_s  = (const float*)d_in[5];
  float* out = (float*)d_out;

  __bf16* kp = (__bf16*)d_ws;                              // 19,922,944 B
  __bf16* vt = (__bf16*)((char*)d_ws + KP_BYTES);          // 21,233,664 B

  pack_kv<<<KPACK_BLOCKS + BH * NKIT, 256, 0, stream>>>(k_mv, k_s, v_mv, v_s, kp, vt);

  dim3 grid(N_ / BM, BH);
  geo_attn_kernel<<<grid, 256, 0, stream>>>(q_mv, q_s, kp, vt, out);
}

// Round 2
// 239.460 us; speedup vs baseline: 1.1316x; 1.0191x over previous
//
#include <hip/hip_runtime.h>
#include <cstdint>
#include <math.h>

// GeometricAttention: B=4,H=8,N=2048, D = 8*16 (mv, IPF signs on q) + 16 (s) = 144
// R5: double-buffered K/V staging with prefetch (stage t+1 issued BEFORE compute t,
// single barrier/iter), BM=256 / 512 threads / 1 block/CU (85KB LDS), XCD-chunked
// block swizzle so each bh's kp/vt stays in one XCD's L2. V-pack reverted to the
// verified vector-write transpose (R4's scalar-write version regressed).

#define BH    32
#define N_    2048
#define DMV   128
#define DS    16
#define D_    144
#define BM    256          // Q rows per block (8 waves x 32 rows)
#define BN    64           // KV rows per iteration
#define NKIT  (N_ / BN)    // 32
#define KSTR  152          // packed K row stride (bf16): 144 data + 8 pad
#define VSTR  72           // packed V^T row stride (bf16): 64 data + 8 pad
#define SVROWS 160         // sVT rows: 144 data + 16 zero pad (dt=4 tile)
#define KCHUNKS (BN * KSTR / 8)   // 1216 16B chunks
#define VCHUNKS (D_ * VSTR / 8)   // 1296 16B chunks
#define KP_BYTES ((size_t)BH * N_ * KSTR * 2)   // 19,922,944
#define QSCALE 0.12022458674074693f  // (1/12) * log2(e)
#define KPACK_BLOCKS (BH * N_ * 19 / 256)       // 4864
#define TSTR  156          // V-pack LDS transpose stride

typedef __bf16 bf16_8 __attribute__((ext_vector_type(8)));
typedef __bf16 bf16_4 __attribute__((ext_vector_type(4)));
typedef __bf16 bf16_2 __attribute__((ext_vector_type(2)));
typedef float  f32x4  __attribute__((ext_vector_type(4)));
typedef float  f32x16 __attribute__((ext_vector_type(16)));

#define GLOAD_LDS16(g, l)                                                     \
  __builtin_amdgcn_global_load_lds(                                           \
      (const __attribute__((address_space(1))) void*)(g),                     \
      (__attribute__((address_space(3))) void*)(l), 16, 0, 0)

__device__ __forceinline__ f32x16 mfma32(bf16_8 a, bf16_8 b, f32x16 c) {
  return __builtin_amdgcn_mfma_f32_32x32x16_bf16(a, b, c, 0, 0, 0);
}

__device__ __forceinline__ bf16_4 cvt4(f32x4 x) {
  bf16_4 w; w[0]=(__bf16)x[0]; w[1]=(__bf16)x[1]; w[2]=(__bf16)x[2]; w[3]=(__bf16)x[3];
  return w;
}

// ---------------- pre-pass: K pack + V^T pack in one launch -------------------------
// blocks [0, KPACK_BLOCKS): K -> bf16 [bh*n][152], one thread = one 16B chunk (19/row)
// blocks [KPACK_BLOCKS, +1024): V^T -> bf16 tile-blocked [bh*32 tiles][144][72]
//   (vector bf16_4 LDS writes row-major, paired scalar reads, bf16_2 global stores)
__global__ __launch_bounds__(256)
void pack_kv(const float* __restrict__ kmv, const float* __restrict__ ks_,
             const float* __restrict__ vmv, const float* __restrict__ vs,
             __bf16* __restrict__ kp, __bf16* __restrict__ vt) {
  __shared__ __align__(16) __bf16 sT[64 * TSTR];   // 19968 B (V branch only)
  const int t = threadIdx.x;
  const int b = blockIdx.x;
  if (b < KPACK_BLOCKS) {
    const unsigned g = b * 256u + t;               // < 65536*19
    const unsigned row = g / 19u, seg = g - row * 19u;
    bf16_8 o;
    if (seg < 16) {
      const f32x4* p = (const f32x4*)(kmv + (size_t)row * DMV + seg * 8);
      f32x4 a = p[0], bb = p[1];
#pragma unroll
      for (int j = 0; j < 8; ++j) o[j] = (__bf16)((j < 4) ? a[j] : bb[j - 4]);
    } else if (seg < 18) {
      const f32x4* p = (const f32x4*)(ks_ + (size_t)row * DS + (seg - 16) * 8);
      f32x4 a = p[0], bb = p[1];
#pragma unroll
      for (int j = 0; j < 8; ++j) o[j] = (__bf16)((j < 4) ? a[j] : bb[j - 4]);
    } else {
#pragma unroll
      for (int j = 0; j < 8; ++j) o[j] = (__bf16)0.0f;
    }
    *(bf16_8*)(kp + (size_t)row * KSTR + seg * 8) = o;
    return;
  }
  // ---- V^T pack ----
  const int tile = b - KPACK_BLOCKS;               // bh*32 + nb
  const int n = t >> 2, c = t & 3;
  const float* mv = vmv + (size_t)(tile * 64 + n) * DMV;
  const float* sv = vs  + (size_t)(tile * 64 + n) * DS;
  __bf16* row = &sT[n * TSTR];
  if (c < 3) {
#pragma unroll
    for (int i = 0; i < 9; ++i)
      *(bf16_4*)&row[c * 36 + 4 * i] = cvt4(*(const f32x4*)(mv + c * 36 + 4 * i));
  } else {
#pragma unroll
    for (int i = 0; i < 5; ++i)
      *(bf16_4*)&row[108 + 4 * i] = cvt4(*(const f32x4*)(mv + 108 + 4 * i));
#pragma unroll
    for (int i = 0; i < 4; ++i)
      *(bf16_4*)&row[128 + 4 * i] = cvt4(*(const f32x4*)(sv + 4 * i));
  }
  __syncthreads();
  __bf16* vtt = vt + (size_t)tile * (D_ * VSTR);
#pragma unroll
  for (int k = 0; k < 18; ++k) {
    int idx = t + 256 * k;                // 4608 = 144 d x 32 j-pairs
    int d = idx >> 5, j = idx & 31;
    bf16_2 p; p[0] = sT[(2 * j) * TSTR + d]; p[1] = sT[(2 * j + 1) * TSTR + d];
    *(bf16_2*)&vtt[d * VSTR + 2 * j] = p; // 128B contiguous per 32 lanes
  }
}

// ---------------- Q fragment load: IPF sign + scale, fp32 -> bf16 (k0 multiple of 8) --
__device__ __forceinline__ bf16_8 load_q_frag(const float* qmv_row, const float* qs_row, int k0) {
  bf16_8 f;
  if (k0 < DMV) {
    const f32x4* p = (const f32x4*)(qmv_row + k0);
    f32x4 a = p[0], b = p[1];
    // IPF = [1,1,-1,-1,-1,-1,-1,-1, 1,1,1,1,1,1,-1,-1]; k0&8 selects which half.
    int hi8 = k0 & 8;
#pragma unroll
    for (int j = 0; j < 8; ++j) {
      float v = (j < 4) ? a[j] : b[j - 4];
      bool pos = hi8 ? (j < 6) : (j < 2);
      f[j] = (__bf16)(v * (pos ? QSCALE : -QSCALE));
    }
  } else {
    const f32x4* p = (const f32x4*)(qs_row + (k0 - DMV));
    f32x4 a = p[0], b = p[1];
#pragma unroll
    for (int j = 0; j < 8; ++j) {
      float v = (j < 4) ? a[j] : b[j - 4];
      f[j] = (__bf16)(v * QSCALE);
    }
  }
  return f;
}

// ---------------- main flash kernel (512 threads, 8 waves x 32 Q-rows) ---------------
__global__ __launch_bounds__(512, 2)
void geo_attn_kernel(const float* __restrict__ q_mv, const float* __restrict__ q_s,
                     const __bf16* __restrict__ kp, const __bf16* __restrict__ vt,
                     float* __restrict__ out)
{
  __shared__ __align__(16) __bf16 sK[2][BN * KSTR];       // 2 x 19456 B
  __shared__ __align__(16) __bf16 sVT[2][SVROWS * VSTR];  // 2 x 23040 B (total 84992)

  const int tid  = threadIdx.x;
  const int w    = tid >> 6;        // wave 0..7
  const int lane = tid & 63;
  const int c32  = lane & 31;
  const int hi   = lane >> 5;
  // XCD-chunked swizzle: all 8 q-blocks of a bh on one XCD (xcd = flat % 8)
  const int flat = blockIdx.x;           // 0..255
  const int xcd  = flat & 7;
  const int jj   = flat >> 3;            // 0..31
  const int bh   = xcd * 4 + (jj & 3);
  const int qb   = jj >> 2;              // 0..7
  const int qbase = qb * BM;
  const size_t bh_n = (size_t)bh * N_;

  // zero the d-pad rows 144..159 of both sVT buffers once (staging never touches them)
  if (tid < 288) {
    int bb = tid / 144, cc = tid - bb * 144;
    f32x4 z = {0.f, 0.f, 0.f, 0.f};
    *(f32x4*)((char*)&sVT[bb][D_ * VSTR] + cc * 16) = z;
  }

  // ---- Q fragments in registers: B-operand layout, col m = c32, k = ks*16 + hi*8 + j
  bf16_8 qf[9];
  {
    const int mrow = qbase + w * 32 + c32;
    const float* qmv_row = q_mv + (bh_n + mrow) * DMV;
    const float* qs_row  = q_s  + (bh_n + mrow) * DS;
#pragma unroll
    for (int ks = 0; ks < 9; ++ks)
      qf[ks] = load_q_frag(qmv_row, qs_row, ks * 16 + hi * 8);
  }

  f32x16 of[5];
#pragma unroll
  for (int dt = 0; dt < 5; ++dt)
#pragma unroll
    for (int r = 0; r < 16; ++r) of[dt][r] = 0.0f;
  float m_i = -INFINITY, l_i = 0.0f;    // per Q-row stat, row m = c32 (both hi copies)

  const __bf16* kbase = kp + bh_n * KSTR;
  const __bf16* vbase = vt + (size_t)bh * NKIT * (D_ * VSTR);

  // ======== staging macro-ish lambda: issue DMA for tile `it` into buffer `bu` ======
  auto stage = [&](int it, int bu) {
    const __bf16* kt  = kbase + (size_t)(it * BN) * KSTR;
    const __bf16* vtt = vbase + (size_t)it * (D_ * VSTR);
    __bf16* dK = &sK[bu][0];
    __bf16* dV = &sVT[bu][0];
#pragma unroll
    for (int s = 0; s < 2; ++s)
      GLOAD_LDS16(kt + (tid + 512 * s) * 8, dK + (tid + 512 * s) * 8);
    if (tid < KCHUNKS - 1024)   // 192: waves 0..2
      GLOAD_LDS16(kt + (tid + 1024) * 8, dK + (tid + 1024) * 8);
#pragma unroll
    for (int s = 0; s < 2; ++s)
      GLOAD_LDS16(vtt + (tid + 512 * s) * 8, dV + (tid + 512 * s) * 8);
    if (tid < VCHUNKS - 1024)   // 272: waves 0..3 + 16 lanes of wave 4
      GLOAD_LDS16(vtt + (tid + 1024) * 8, dV + (tid + 1024) * 8);
  };

  stage(0, 0);           // prologue
  __syncthreads();       // compiler drains vmcnt(0) -> tile 0 resident

  for (int it = 0; it < NKIT; ++it) {
    const int cur = it & 1;
    if (it + 1 < NKIT) stage(it + 1, cur ^ 1);   // prefetch: hidden under compute

    // ======== S^T = K Q^T : sf[nt] rows n = nt*32 + (r&3)+8*(r>>2)+4*hi, cols m=c32 ==
    f32x16 sf[2];
#pragma unroll
    for (int nt = 0; nt < 2; ++nt)
#pragma unroll
      for (int r = 0; r < 16; ++r) sf[nt][r] = 0.0f;
    __builtin_amdgcn_s_setprio(1);
#pragma unroll
    for (int ks = 0; ks < 9; ++ks) {
      bf16_8 kb0 = *(const bf16_8*)&sK[cur][(c32)      * KSTR + ks * 16 + hi * 8];
      bf16_8 kb1 = *(const bf16_8*)&sK[cur][(32 + c32) * KSTR + ks * 16 + hi * 8];
      sf[0] = mfma32(kb0, qf[ks], sf[0]);
      sf[1] = mfma32(kb1, qf[ks], sf[1]);
    }
    __builtin_amdgcn_s_setprio(0);

    // ======== online softmax: row m = c32 fully lane-local (32 vals) + 1 shuffle ====
    float al = 1.0f, m_use;
    {
      float mx = sf[0][0];
#pragma unroll
      for (int r = 1; r < 16; ++r) mx = fmaxf(mx, sf[0][r]);
#pragma unroll
      for (int r = 0; r < 16; ++r) mx = fmaxf(mx, sf[1][r]);
      mx = fmaxf(mx, __shfl_xor(mx, 32));

      // T13 deferred rescale: keep old max while growth <= 8 (P bounded by 2^8)
      if (__all(mx <= m_i + 8.0f)) {
        m_use = m_i;
      } else {
        float mnew = fmaxf(m_i, mx);
        al = __builtin_amdgcn_exp2f(m_i - mnew);
        m_i = mnew; m_use = mnew;
        // redistribute al to O-row indexing (row m' = (r&3)+8*(r>>2)+4*hi)
#pragma unroll
        for (int r = 0; r < 16; ++r) {
          float a = __shfl(al, (r & 3) + 8 * (r >> 2) + 4 * hi);
#pragma unroll
          for (int dt = 0; dt < 5; ++dt) of[dt][r] *= a;
        }
      }
      float rs = 0.0f;
#pragma unroll
      for (int nt = 0; nt < 2; ++nt)
#pragma unroll
        for (int r = 0; r < 16; ++r) {
          float p = __builtin_amdgcn_exp2f(sf[nt][r] - m_use);
          sf[nt][r] = p;
          rs += p;
        }
      rs += __shfl_xor(rs, 32);
      l_i = l_i * al + rs;
    }

    // ======== O += P V, P assembled in-register (cvt_pk + permlane32_swap) ==========
#pragma unroll
    for (int ks = 0; ks < 4; ++ks) {
      const int nt = ks >> 1;
      const int Ra = 8 * (ks & 1);
      unsigned x0, x1, y0, y1;
      asm("v_cvt_pk_bf16_f32 %0, %1, %2" : "=v"(x0) : "v"(sf[nt][Ra + 0]), "v"(sf[nt][Ra + 1]));
      asm("v_cvt_pk_bf16_f32 %0, %1, %2" : "=v"(x1) : "v"(sf[nt][Ra + 2]), "v"(sf[nt][Ra + 3]));
      asm("v_cvt_pk_bf16_f32 %0, %1, %2" : "=v"(y0) : "v"(sf[nt][Ra + 4]), "v"(sf[nt][Ra + 5]));
      asm("v_cvt_pk_bf16_f32 %0, %1, %2" : "=v"(y1) : "v"(sf[nt][Ra + 6]), "v"(sf[nt][Ra + 7]));
      auto s0 = __builtin_amdgcn_permlane32_swap(x0, y0, false, false);
      auto s1 = __builtin_amdgcn_permlane32_swap(x1, y1, false, false);
      union { unsigned u[4]; bf16_8 v; } pu;
      pu.u[0] = s0[0]; pu.u[1] = s1[0]; pu.u[2] = s0[1]; pu.u[3] = s1[1];
      __builtin_amdgcn_s_setprio(1);
#pragma unroll
      for (int dt = 0; dt < 5; ++dt) {
        bf16_8 vb = *(const bf16_8*)&sVT[cur][(dt * 32 + c32) * VSTR + ks * 16 + hi * 8];
        of[dt] = mfma32(pu.v, vb, of[dt]);
      }
      __builtin_amdgcn_s_setprio(0);
    }
    __syncthreads();  // drains prefetch DMA + all sK/sVT[cur] reads before reuse
  }

  // ======== epilogue: O /= l (redistributed to O-rows), write fp32 ========
  float* out_mv = out;
  float* out_s  = out + (size_t)BH * N_ * DMV;
#pragma unroll
  for (int r = 0; r < 16; ++r) {
    const int ml  = (r & 3) + 8 * (r >> 2) + 4 * hi;
    const float linv = __builtin_amdgcn_rcpf(__shfl(l_i, ml));
    const int row = qbase + w * 32 + ml;
#pragma unroll
    for (int dt = 0; dt < 4; ++dt)
      out_mv[(bh_n + row) * DMV + dt * 32 + c32] = of[dt][r] * linv;
    if (c32 < DS)
      out_s[(bh_n + row) * DS + c32] = of[4][r] * linv;
  }
}

extern "C" void kernel_launch(void* const* d_in, const int* in_sizes, int n_in,
                              void* d_out, int out_size, void* d_ws, size_t ws_size,
                              hipStream_t stream) {
  (void)in_sizes; (void)n_in; (void)out_size; (void)ws_size;
  const float* q_mv = (const float*)d_in[0];
  const float* k_mv = (const float*)d_in[1];
  const float* v_mv = (const float*)d_in[2];
  const float* q_s  = (const float*)d_in[3];
  const float* k_s  = (const float*)d_in[4];
  const float* v_s  = (const float*)d_in[5];
  float* out = (float*)d_out;

  __bf16* kp = (__bf16*)d_ws;                              // 19,922,944 B
  __bf16* vt = (__bf16*)((char*)d_ws + KP_BYTES);          // 21,233,664 B

  pack_kv<<<KPACK_BLOCKS + BH * NKIT, 256, 0, stream>>>(k_mv, k_s, v_mv, v_s, kp, vt);

  geo_attn_kernel<<<dim3(256), 512, 0, stream>>>(q_mv, q_s, kp, vt, out);
}